// Round 1
// baseline (641.622 us; speedup 1.0000x reference)
//
#include <hip/hip_runtime.h>

#define NF 64
#define ND 128

// out[b] = sum_{i<j} w[i,j] * <x[b,i,:], x[b,j,:]>
// Reformulated per d-column: out[b] = sum_d  v^T W_upper v,  v = x[b,:,d]
// One lane owns one column d (64 values in VGPRs). 2080 FMAs/lane/column.
__global__ __launch_bounds__(256) void wfi_kernel(const float* __restrict__ x,
                                                  const float* __restrict__ w,
                                                  float* __restrict__ out) {
    const int tid  = threadIdx.x;
    const int wave = tid >> 6;        // 0..3
    const int lane = tid & 63;
    const int bloc = wave >> 1;       // which of the 2 batches this block handles
    const int d0   = (wave & 1) << 6; // 0 or 64
    const int b    = blockIdx.x * 2 + bloc;

    const float* xb = x + (size_t)b * (NF * ND) + d0 + lane;

    // Load column d = d0+lane : x[b, i*ND + d], coalesced across lanes.
    float v[NF];
#pragma unroll
    for (int i = 0; i < NF; ++i) v[i] = xb[(size_t)i * ND];

    // acc = sum_j v[j] * (sum_{i<j} w[i][j] * v[i])
    float acc = 0.f;
#pragma unroll
    for (int j = 1; j < NF; ++j) {
        float u = 0.f;
#pragma unroll
        for (int i = 0; i < j; ++i) u = fmaf(w[i * NF + j], v[i], u);
        acc = fmaf(u, v[j], acc);
    }

    // 64-lane wave reduction
#pragma unroll
    for (int off = 32; off >= 1; off >>= 1) acc += __shfl_down(acc, off, 64);

    __shared__ float part[4];
    if (lane == 0) part[wave] = acc;
    __syncthreads();
    if (tid < 2) out[blockIdx.x * 2 + tid] = part[2 * tid] + part[2 * tid + 1];
}

extern "C" void kernel_launch(void* const* d_in, const int* in_sizes, int n_in,
                              void* d_out, int out_size, void* d_ws, size_t ws_size,
                              hipStream_t stream) {
    const float* x = (const float*)d_in[0];
    const float* w = (const float*)d_in[1];
    float* out = (float*)d_out;

    const int B = in_sizes[0] / (NF * ND);   // 8192
    dim3 grid(B / 2);                        // 2 batches per 256-thread block
    dim3 block(256);
    wfi_kernel<<<grid, block, 0, stream>>>(x, w, out);
}

// Round 3
// 391.683 us; speedup vs baseline: 1.6381x; 1.6381x over previous
//
#include <hip/hip_runtime.h>

#define NF 64
#define ND 128

typedef __attribute__((ext_vector_type(8))) short bf16x8;  // MFMA A/B frag (8 bf16)
typedef __attribute__((ext_vector_type(4))) float f32x4;   // MFMA C/D frag

// fp32 -> bf16 round-to-nearest-even
__device__ __forceinline__ short f2bf(float f) {
    union { float f; unsigned u; } v; v.f = f;
    unsigned r = (v.u + 0x7FFFu + ((v.u >> 16) & 1u)) >> 16;
    return (short)r;
}

// out[b] = sum_{i<j} w[i,j] <x_i, x_j>  =  sum_{j,d} Y[j,d] * X[j,d],
// Y = W_eff^T X[b],  W_eff[i,j] = w[i,j]*[i<j].
// One wave per batch. Per-batch GEMM: M=64(j) x N=128(d) x K=64(i) via
// 4x8x2 = 64 mfma_f32_16x16x32_bf16. No LDS; dot re-reads X while L1-hot.
__global__ __launch_bounds__(256, 4) void wfi_mfma(const float* __restrict__ x,
                                                   const float* __restrict__ w,
                                                   float* __restrict__ out,
                                                   int Btot) {
    const int tid  = threadIdx.x;
    const int wv   = tid >> 6;
    const int lane = tid & 63;
    const int lo   = lane & 15;   // MFMA m/n/col lane index
    const int hi   = lane >> 4;   // 0..3
    const int b    = blockIdx.x * 4 + wv;
    if (b >= Btot) return;

    // ---- A fragments: A[m=j, k=i] = (i<j) ? w[i,j] : 0 ----
    // Assumed (lane,e)->k map: k = hi*8 + e (tile-local). The same map is used
    // for B frags, so any internal hardware k-permutation cancels.
    bf16x8 afr[4][2];
#pragma unroll
    for (int jt = 0; jt < 4; ++jt) {
        const int j = jt * 16 + lo;
#pragma unroll
        for (int kt = 0; kt < 2; ++kt) {
#pragma unroll
            for (int e = 0; e < 8; ++e) {
                const int i = kt * 32 + hi * 8 + e;
                const float wval = (i < j) ? w[i * NF + j] : 0.f;
                afr[jt][kt][e] = f2bf(wval);
            }
        }
    }

    const float* __restrict__ xb = x + (size_t)b * (NF * ND);
    float res = 0.f;

#pragma unroll
    for (int dt = 0; dt < 8; ++dt) {
        const int d = dt * 16 + lo;

        // ---- B fragments: B[k=i, n=d] = X[i,d] ----
        bf16x8 bfr[2];
#pragma unroll
        for (int kt = 0; kt < 2; ++kt) {
#pragma unroll
            for (int e = 0; e < 8; ++e) {
                const int i = kt * 32 + hi * 8 + e;
                bfr[kt][e] = f2bf(xb[i * ND + d]);
            }
        }

        // ---- Y tile: 4 j-tiles x 2 k-tiles ----
        f32x4 acc[4] = {{0,0,0,0},{0,0,0,0},{0,0,0,0},{0,0,0,0}};
#pragma unroll
        for (int jt = 0; jt < 4; ++jt) {
#pragma unroll
            for (int kt = 0; kt < 2; ++kt) {
                acc[jt] = __builtin_amdgcn_mfma_f32_16x16x32_bf16(
                    afr[jt][kt], bfr[kt], acc[jt], 0, 0, 0);
            }
        }

        // ---- dot with X: C/D layout (verified): col = lane&15, row = hi*4+r ----
#pragma unroll
        for (int jt = 0; jt < 4; ++jt) {
#pragma unroll
            for (int r = 0; r < 4; ++r) {
                const int j = jt * 16 + hi * 4 + r;
                res = fmaf(acc[jt][r], xb[j * ND + d], res);  // L1-hot re-read
            }
        }
    }

    // ---- 64-lane wave reduction ----
#pragma unroll
    for (int off = 32; off >= 1; off >>= 1) res += __shfl_down(res, off, 64);
    if (lane == 0) out[b] = res;
}

extern "C" void kernel_launch(void* const* d_in, const int* in_sizes, int n_in,
                              void* d_out, int out_size, void* d_ws, size_t ws_size,
                              hipStream_t stream) {
    const float* x = (const float*)d_in[0];
    const float* w = (const float*)d_in[1];
    float* out = (float*)d_out;

    const int B = in_sizes[0] / (NF * ND);   // 8192
    dim3 grid((B + 3) / 4);                  // 4 batches (waves) per block
    dim3 block(256);
    wfi_mfma<<<grid, block, 0, stream>>>(x, w, out, B);
}

// Round 4
// 353.400 us; speedup vs baseline: 1.8156x; 1.1083x over previous
//
#include <hip/hip_runtime.h>

#define NF 64
#define ND 128

typedef __attribute__((ext_vector_type(8))) short bf16x8;  // MFMA A/B frag (8 bf16)
typedef __attribute__((ext_vector_type(4))) float f32x4;   // MFMA C/D frag / float4 load

// fp32 -> bf16 round-to-nearest-even
__device__ __forceinline__ short f2bf(float f) {
    union { float f; unsigned u; } v; v.f = f;
    unsigned r = (v.u + 0x7FFFu + ((v.u >> 16) & 1u)) >> 16;
    return (short)r;
}

// out[b] = sum_{i<j} w[i,j] * G[i,j],  G = X X^T (contraction over d!).
// One wave per batch. Fragments are rows of X (8 consecutive fp32 -> 2x
// dwordx4), X read exactly once, A-frag == B-frag registers. Upper-triangle
// tiles only: 10 tiles x 4 ktiles = 40 mfma_f32_16x16x32_bf16 per batch.
__global__ __launch_bounds__(256) void wfi_gram(const float* __restrict__ x,
                                                const float* __restrict__ w,
                                                float* __restrict__ out,
                                                int Btot) {
    const int tid  = threadIdx.x;
    const int wv   = tid >> 6;
    const int lane = tid & 63;
    const int lo   = lane & 15;   // m or n index within 16-tile
    const int hi   = lane >> 4;   // 0..3, k-group
    const int b    = blockIdx.x * 4 + wv;
    if (b >= Btot) return;

    const float* __restrict__ xb = x + (size_t)b * (NF * ND);

    // frag[t][kt] holds X[t*16+lo, kt*32 + hi*8 + e], e=0..7 (row-major, vectorized)
    bf16x8 xf[4][4];
#pragma unroll
    for (int t = 0; t < 4; ++t) {
        const float* rowp = xb + (size_t)(t * 16 + lo) * ND + hi * 8;
#pragma unroll
        for (int kt = 0; kt < 4; ++kt) {
            const f32x4 a = *(const f32x4*)(rowp + kt * 32);
            const f32x4 c = *(const f32x4*)(rowp + kt * 32 + 4);
            bf16x8 f;
            f[0] = f2bf(a[0]); f[1] = f2bf(a[1]); f[2] = f2bf(a[2]); f[3] = f2bf(a[3]);
            f[4] = f2bf(c[0]); f[5] = f2bf(c[1]); f[6] = f2bf(c[2]); f[7] = f2bf(c[3]);
            xf[t][kt] = f;
        }
    }

    float res = 0.f;
    // Only tiles with mt <= nt contribute (i<j mask kills mt>nt entirely).
#pragma unroll
    for (int mt = 0; mt < 4; ++mt) {
#pragma unroll
        for (int nt = mt; nt < 4; ++nt) {
            f32x4 acc = {0.f, 0.f, 0.f, 0.f};
#pragma unroll
            for (int kt = 0; kt < 4; ++kt)
                acc = __builtin_amdgcn_mfma_f32_16x16x32_bf16(xf[mt][kt], xf[nt][kt],
                                                              acc, 0, 0, 0);
            // C/D map (m89-verified): G[mt*16 + hi*4 + r, nt*16 + lo]
#pragma unroll
            for (int r = 0; r < 4; ++r) {
                const int i = mt * 16 + hi * 4 + r;
                const int j = nt * 16 + lo;
                float wij;
                if (mt == nt)
                    wij = (hi * 4 + r < lo) ? w[i * NF + j] : 0.f;  // diagonal tile: mask i<j
                else
                    wij = w[i * NF + j];                            // strictly upper tile
                res = fmaf(acc[r], wij, res);
            }
        }
    }

    // 64-lane wave reduction
#pragma unroll
    for (int off = 32; off >= 1; off >>= 1) res += __shfl_down(res, off, 64);
    if (lane == 0) out[b] = res;
}

extern "C" void kernel_launch(void* const* d_in, const int* in_sizes, int n_in,
                              void* d_out, int out_size, void* d_ws, size_t ws_size,
                              hipStream_t stream) {
    const float* x = (const float*)d_in[0];
    const float* w = (const float*)d_in[1];
    float* out = (float*)d_out;

    const int B = in_sizes[0] / (NF * ND);   // 8192
    dim3 grid((B + 3) / 4);                  // 4 batches (one per wave) per block
    dim3 block(256);
    wfi_gram<<<grid, block, 0, stream>>>(x, w, out, B);
}